// Round 7
// baseline (317.960 us; speedup 1.0000x reference)
//
#include <hip/hip_runtime.h>

// MTTT attention, MI355X gfx950 — ROUND 7: ablation round.
// Real pipeline identical to round 6 (passed, absmax 0.0117).
// Extra dispatches g_ab1..g_ab4 ablate the qkv GEMM's phase components;
// they write garbage into qkvb which the real g_main256 then overwrites,
// so the final output is unchanged and deterministic.

#define SEQ    1024
#define NBATCH 8
#define DIMC   1024
#define NHEAD  16
#define HDIM   64
#define MROWS  8192      // NBATCH*SEQ
#define NQKV   3072

typedef __attribute__((ext_vector_type(8))) __bf16 bf16x8;
typedef __attribute__((ext_vector_type(4))) float  f32x4;

__device__ __forceinline__ unsigned short f2b(float f) {
  union { float f; unsigned int u; } v; v.f = f;
  unsigned int r = (v.u + 0x7FFFu + ((v.u >> 16) & 1u)) >> 16; // RNE
  return (unsigned short)r;
}
__device__ __forceinline__ float b2f(unsigned short u) {
  union { unsigned int u; float f; } v; v.u = ((unsigned int)u) << 16;
  return v.f;
}

// async global->LDS, 16B per lane; LDS dest = wave-uniform base + lane*16
__device__ __forceinline__ void load_lds16(const void* g, void* l) {
  __builtin_amdgcn_global_load_lds(
      (__attribute__((address_space(1))) void*)(void*)(g),
      (__attribute__((address_space(3))) void*)(l), 16, 0, 0);
}

#define FENCE  asm volatile("" ::: "memory")
#define BAR    __builtin_amdgcn_s_barrier()
#define PRIO1  __builtin_amdgcn_s_setprio(1)
#define PRIO0  __builtin_amdgcn_s_setprio(0)
#define SCHED0 __builtin_amdgcn_sched_barrier(0)

// ---------------- fp32 -> bf16 convert (vectorized) ----------------
__global__ __launch_bounds__(256) void cvt_bf16(const float* __restrict__ in,
                                                unsigned short* __restrict__ out,
                                                int n4) {
  int i = blockIdx.x * 256 + threadIdx.x;
  if (i >= n4) return;
  float4 v = ((const float4*)in)[i];
  ushort4 o;
  o.x = f2b(v.x); o.y = f2b(v.y); o.z = f2b(v.z); o.w = f2b(v.w);
  ((ushort4*)out)[i] = o;
}

// ------------- fp32 (R x Cc) -> bf16 transposed (Cc x R) -------------
__global__ __launch_bounds__(256) void transpose_cvt(const float* __restrict__ in,
                                                     unsigned short* __restrict__ out,
                                                     int R, int Cc) {
  __shared__ unsigned short tile[32][33];
  int c0 = blockIdx.x * 32, r0 = blockIdx.y * 32;
  int tx = threadIdx.x, ty = threadIdx.y;
  for (int i = ty; i < 32; i += 8)
    tile[i][tx] = f2b(in[(size_t)(r0 + i) * Cc + c0 + tx]);
  __syncthreads();
  for (int i = ty; i < 32; i += 8)
    out[(size_t)(c0 + i) * R + r0 + tx] = tile[tx][i];
}

// =====================================================================
// 8-phase NT bf16 GEMM body (round-6 schedule, verified correct), with
// compile-time ablation gates:
//   V=0: full (real)         V=1: no staging (reads+MFMA+syncs)
//   V=2: no ds_reads         V=3: no MFMA (reads kept live via asm)
//   V=4: MFMA+syncs only (no reads, no stages)
// All variants keep identical barrier/vmcnt/setprio structure.
// =====================================================================
template <int BM, int STORE_F32, int V>
__device__ __forceinline__ void gemm_body(const unsigned short* __restrict__ A,
                                          const unsigned short* __restrict__ BT,
                                          void* __restrict__ Cout,
                                          const float* __restrict__ bias,
                                          int N, int NBN) {
  constexpr bool DO_READ  = (V == 0 || V == 1 || V == 3);
  constexpr bool DO_STAGE = (V == 0 || V == 2 || V == 3);
  constexpr bool DO_MFMA  = (V != 3);

  constexpr int MI = BM / 32;          // m-frags per wave
  constexpr int MH = MI / 2;           // m-frags per quadrant
  constexpr int ABYTES = BM * 128;     // A K-tile bytes (BM x 64 x bf16)
  constexpr int BUFB = ABYTES + 32768; // + B K-tile (256 x 64 x bf16)
  constexpr int ACALLS = BM / 128;     // gload_lds calls per A half-tile

  extern __shared__ __align__(16) char ldsb[];

  const int tid = threadIdx.x;
  const int lane = tid & 63, wave = tid >> 6;
  const int wr = wave >> 2, wc = wave & 3;
  const int frow = lane & 15;
  const int g4 = lane >> 4;
  const int cz0 = (g4 ^ (lane & 7)) * 16;        // kk=0 swizzled chunk byte
  const int cz1 = ((4 | g4) ^ (lane & 7)) * 16;  // kk=1

  // XCD-aware bijective block swizzle (gridDim.x % 8 == 0)
  const int cpx = gridDim.x >> 3;
  const int wg = (blockIdx.x & 7) * cpx + (blockIdx.x >> 3);
  const int bm = wg / NBN, bn = wg % NBN;
  const size_t m0 = (size_t)bm * BM, n0 = (size_t)bn * 256;

  const int srow = tid >> 3;
  const int scol = ((tid & 7) ^ ((tid >> 3) & 7)) * 8;  // element offset
  const unsigned short* srcA = A + (m0 + srow) * 1024 + scol;
  const unsigned short* srcB = BT + (n0 + srow) * 1024 + scol;

  const int aBase = (wr * (BM / 2) + frow) * 128;
  const int bBase = (wc * 64 + frow) * 128;

  f32x4 acc[MI][4];
  if (STORE_F32) {
#pragma unroll
    for (int j = 0; j < 4; ++j) {
      float4 bv = *(const float4*)&bias[n0 + wc * 64 + j * 16 + g4 * 4];
      f32x4 t; t[0] = bv.x; t[1] = bv.y; t[2] = bv.z; t[3] = bv.w;
#pragma unroll
      for (int i = 0; i < MI; ++i) acc[i][j] = t;
    }
  } else {
#pragma unroll
    for (int i = 0; i < MI; ++i)
#pragma unroll
      for (int j = 0; j < 4; ++j) acc[i][j] = f32x4{0.f, 0.f, 0.f, 0.f};
  }

  auto stageA = [&](int buf_, int h_, int tt_) {
    char* dst = ldsb + buf_ * BUFB + h_ * (ABYTES / 2) + wave * 1024;
    const unsigned short* s = srcA + (size_t)(h_ * (BM / 2)) * 1024 + tt_ * 64;
    load_lds16(s, dst);
    if constexpr (ACALLS == 2) load_lds16(s + 65536, dst + 8192);
  };
  auto stageB = [&](int buf_, int h_, int tt_) {
    char* dst = ldsb + buf_ * BUFB + ABYTES + h_ * 16384 + wave * 1024;
    const unsigned short* s = srcB + (size_t)(h_ * 128) * 1024 + tt_ * 64;
    load_lds16(s, dst);
    load_lds16(s + 65536, dst + 8192);
  };

#define READ_A(buf_, mh_, dst_) do {                                     \
    const char* ab_ = ldsb + (buf_) * BUFB + aBase + (mh_) * (MH * 2048);\
    _Pragma("unroll") for (int fi = 0; fi < MH; ++fi) {                  \
      dst_[fi][0] = *(const bf16x8*)(ab_ + fi * 2048 + cz0);             \
      dst_[fi][1] = *(const bf16x8*)(ab_ + fi * 2048 + cz1); }           \
  } while (0)

#define READ_B(buf_, nh_, dst_) do {                                     \
    const char* bb_ = ldsb + (buf_) * BUFB + ABYTES + bBase + (nh_) * 4096;\
    _Pragma("unroll") for (int fj = 0; fj < 2; ++fj) {                   \
      dst_[fj][0] = *(const bf16x8*)(bb_ + fj * 2048 + cz0);             \
      dst_[fj][1] = *(const bf16x8*)(bb_ + fj * 2048 + cz1); }           \
  } while (0)

  // keep-alive for V=3 (no-MFMA) so ds_reads aren't DCE'd (no addr-taken)
#define KEEPA(d_) do { if constexpr (V == 3) {                           \
    _Pragma("unroll") for (int fi = 0; fi < MH; ++fi)                    \
    _Pragma("unroll") for (int kk = 0; kk < 2; ++kk) {                   \
      f32x4 kt_ = __builtin_bit_cast(f32x4, d_[fi][kk]);                 \
      asm volatile("" :: "v"(kt_[0]), "v"(kt_[1]), "v"(kt_[2]), "v"(kt_[3])); } } } while (0)
#define KEEPB(d_) do { if constexpr (V == 3) {                           \
    _Pragma("unroll") for (int fj = 0; fj < 2; ++fj)                     \
    _Pragma("unroll") for (int kk = 0; kk < 2; ++kk) {                   \
      f32x4 kt_ = __builtin_bit_cast(f32x4, d_[fj][kk]);                 \
      asm volatile("" :: "v"(kt_[0]), "v"(kt_[1]), "v"(kt_[2]), "v"(kt_[3])); } } } while (0)

#define MFMAQ(mh_, nh_, as_, bs_) do { if constexpr (DO_MFMA) {          \
    PRIO1;                                                               \
    _Pragma("unroll") for (int fi = 0; fi < MH; ++fi)                    \
    _Pragma("unroll") for (int fj = 0; fj < 2; ++fj)                     \
    _Pragma("unroll") for (int kk = 0; kk < 2; ++kk)                     \
      acc[(mh_) * MH + fi][(nh_) * 2 + fj] =                             \
        __builtin_amdgcn_mfma_f32_16x16x32_bf16(bs_[fj][kk], as_[fi][kk],\
            acc[(mh_) * MH + fi][(nh_) * 2 + fj], 0, 0, 0);              \
    PRIO0; } } while (0)

#define VMW(st_) do {                                                    \
    if (st_) {                                                           \
      if constexpr (BM == 256)                                           \
        asm volatile("s_waitcnt vmcnt(4)" ::: "memory");                 \
      else                                                               \
        asm volatile("s_waitcnt vmcnt(3)" ::: "memory");                 \
    } else {                                                             \
      asm volatile("s_waitcnt vmcnt(0)" ::: "memory");                   \
    }                                                                    \
  } while (0)

  bf16x8 aX[MH][2], aY[MH][2], b0[2][2], b1[2][2];

  // ---- prologue: buf0 <- tile0 full; buf1 <- tile1 {B0,A0,A1} ----
  stageB(0, 0, 0); stageA(0, 0, 0); stageA(0, 1, 0); stageB(0, 1, 0);
  stageB(1, 0, 1); stageA(1, 0, 1); stageA(1, 1, 1);
  if constexpr (BM == 256) asm volatile("s_waitcnt vmcnt(6)" ::: "memory");
  else                     asm volatile("s_waitcnt vmcnt(4)" ::: "memory");
  FENCE; BAR;
  READ_A(0, 0, aX); READ_B(0, 0, b0);
  if constexpr (V == 2 || V == 4) { READ_A(0, 1, aY); READ_B(0, 1, b1); }
  asm volatile("s_waitcnt lgkmcnt(0)" ::: "memory");
  SCHED0;
  FENCE; BAR;

  // 16 K-tiles; iteration = 2 K-tiles (t0=2it->buf0, t1=2it+1->buf1)
#pragma unroll 1
  for (int it = 0; it < 8; ++it) {
    const int st = (it < 7);
    const int t1 = 2 * it + 1, t2 = 2 * it + 2, t3 = 2 * it + 3;
    // P1
    if constexpr (DO_READ) { READ_B(0, 1, b1); KEEPB(b1); }
    if constexpr (DO_STAGE) stageB(1, 1, t1);
    SCHED0;
    MFMAQ(0, 0, aX, b0); VMW(st); FENCE; BAR;
    // P2
    if constexpr (DO_READ) { READ_A(0, 1, aY); KEEPA(aY); }
    if constexpr (DO_STAGE) if (st) stageB(0, 0, t2);
    SCHED0;
    MFMAQ(0, 1, aX, b1); VMW(st); FENCE; BAR;
    // P3
    if constexpr (DO_READ) { READ_A(1, 0, aX); KEEPA(aX); }
    if constexpr (DO_STAGE) if (st) stageA(0, 0, t2);
    SCHED0;
    MFMAQ(1, 0, aY, b0); VMW(st); FENCE; BAR;
    // P4
    if constexpr (DO_READ) { READ_B(1, 0, b0); KEEPB(b0); }
    if constexpr (DO_STAGE) if (st) stageA(0, 1, t2);
    SCHED0;
    MFMAQ(1, 1, aY, b1); VMW(st); FENCE; BAR;
    // P5
    if constexpr (DO_READ) { READ_B(1, 1, b1); KEEPB(b1); }
    if constexpr (DO_STAGE) if (st) stageB(0, 1, t2);
    SCHED0;
    MFMAQ(0, 0, aX, b0); VMW(st); FENCE; BAR;
    // P6
    if constexpr (DO_READ) { READ_A(1, 1, aY); KEEPA(aY); }
    if constexpr (DO_STAGE) if (st) stageB(1, 0, t3);
    SCHED0;
    MFMAQ(0, 1, aX, b1); VMW(st); FENCE; BAR;
    // P7
    if constexpr (DO_READ) if (st) { READ_A(0, 0, aX); KEEPA(aX); }
    if constexpr (DO_STAGE) if (st) stageA(1, 0, t3);
    SCHED0;
    MFMAQ(1, 0, aY, b0); VMW(st); FENCE; BAR;
    // P8
    if constexpr (DO_READ) if (st) { READ_B(0, 0, b0); KEEPB(b0); }
    if constexpr (DO_STAGE) if (st) stageA(1, 1, t3);
    SCHED0;
    MFMAQ(1, 1, aY, b1); VMW(st); FENCE; BAR;
  }
#undef READ_A
#undef READ_B
#undef KEEPA
#undef KEEPB
#undef MFMAQ
#undef VMW

  // epilogue
  const size_t mbase = m0 + wr * (BM / 2) + frow;
  const size_t nbase = n0 + wc * 64 + g4 * 4;
  if (STORE_F32) {
    float* C = (float*)Cout;
#pragma unroll
    for (int i = 0; i < MI; ++i)
#pragma unroll
      for (int j = 0; j < 4; ++j) {
        float4 o; o.x = acc[i][j][0]; o.y = acc[i][j][1];
        o.z = acc[i][j][2]; o.w = acc[i][j][3];
        *(float4*)&C[(mbase + i * 16) * N + nbase + j * 16] = o;
      }
  } else {
    unsigned short* C = (unsigned short*)Cout;
#pragma unroll
    for (int i = 0; i < MI; ++i)
#pragma unroll
      for (int j = 0; j < 4; ++j) {
        ushort4 o; o.x = f2b(acc[i][j][0]); o.y = f2b(acc[i][j][1]);
        o.z = f2b(acc[i][j][2]); o.w = f2b(acc[i][j][3]);
        *(ushort4*)&C[(mbase + i * 16) * N + nbase + j * 16] = o;
      }
  }
}

__global__ __launch_bounds__(512, 2) void g_main256(const unsigned short* __restrict__ A,
                                                    const unsigned short* __restrict__ BT,
                                                    void* __restrict__ C,
                                                    const float* __restrict__ bias, int N, int NBN) {
  gemm_body<256, 0, 0>(A, BT, C, bias, N, NBN);
}
__global__ __launch_bounds__(512, 2) void g_main128(const unsigned short* __restrict__ A,
                                                    const unsigned short* __restrict__ BT,
                                                    void* __restrict__ C,
                                                    const float* __restrict__ bias, int N, int NBN) {
  gemm_body<128, 1, 0>(A, BT, C, bias, N, NBN);
}
__global__ __launch_bounds__(512, 2) void g_ab1(const unsigned short* __restrict__ A,
                                                const unsigned short* __restrict__ BT,
                                                void* __restrict__ C,
                                                const float* __restrict__ bias, int N, int NBN) {
  gemm_body<256, 0, 1>(A, BT, C, bias, N, NBN);  // no staging
}
__global__ __launch_bounds__(512, 2) void g_ab2(const unsigned short* __restrict__ A,
                                                const unsigned short* __restrict__ BT,
                                                void* __restrict__ C,
                                                const float* __restrict__ bias, int N, int NBN) {
  gemm_body<256, 0, 2>(A, BT, C, bias, N, NBN);  // no ds_reads
}
__global__ __launch_bounds__(512, 2) void g_ab3(const unsigned short* __restrict__ A,
                                                const unsigned short* __restrict__ BT,
                                                void* __restrict__ C,
                                                const float* __restrict__ bias, int N, int NBN) {
  gemm_body<256, 0, 3>(A, BT, C, bias, N, NBN);  // no MFMA
}
__global__ __launch_bounds__(512, 2) void g_ab4(const unsigned short* __restrict__ A,
                                                const unsigned short* __restrict__ BT,
                                                void* __restrict__ C,
                                                const float* __restrict__ bias, int N, int NBN) {
  gemm_body<256, 0, 4>(A, BT, C, bias, N, NBN);  // MFMA+syncs only
}

// ------------- k,v: qkv layout (m, 3C) -> per-head d-major [bh][d][N] -------------
__global__ __launch_bounds__(256) void transpose_kv(const unsigned short* __restrict__ qkvb,
                                                    unsigned short* __restrict__ kt,
                                                    unsigned short* __restrict__ vt) {
  __shared__ unsigned short tile[64][80];  // stride 160B: 16B-aligned rows
  const int nc = blockIdx.x * 64;
  const int bh = blockIdx.y;
  const int which = blockIdx.z;           // 0 -> k (col base C), 1 -> v (col base 2C)
  const int b = bh >> 4, h = bh & 15;
  const int tid = threadIdx.x;
  const unsigned short* src = qkvb + (size_t)(b * SEQ + nc) * NQKV + (which + 1) * DIMC + h * HDIM;
  for (int idx = tid; idx < 512; idx += 256) {
    int rr = idx >> 3, ss = (idx & 7) * 8;
    *(uint4*)&tile[rr][ss] = *(const uint4*)&src[(size_t)rr * NQKV + ss];
  }
  __syncthreads();
  unsigned short* dst = (which ? vt : kt) + (size_t)bh * HDIM * SEQ;
  for (int idx = tid; idx < 512; idx += 256) {
    int dd = idx >> 3, ns = (idx & 7) * 8;
    alignas(16) unsigned short tmp[8];
#pragma unroll
    for (int jj = 0; jj < 8; ++jj) tmp[jj] = tile[ns + jj][dd];
    *(uint4*)&dst[(size_t)dd * SEQ + nc + ns] = *(const uint4*)tmp;
  }
}

// ------------- per-(b,h): G,P via MFMA + mk,mv + 4 GD iters -> W^T (bf16), b -------------
__global__ __launch_bounds__(256) void stats_gd(const unsigned short* __restrict__ kt,
                                                const unsigned short* __restrict__ vt,
                                                unsigned short* __restrict__ Wtb,
                                                float* __restrict__ bvec) {
  __shared__ float Gs[64][68];
  __shared__ float Ps[64][68];
  __shared__ float Ws[64][68];
  __shared__ float mkp[4][64], mvp[4][64];
  __shared__ float mks[64], mvs[64], bs[64];

  const int bh = blockIdx.x;
  const int tid = threadIdx.x;
  const int lane = tid & 63, wave = tid >> 6;
  const unsigned short* kb = kt + (size_t)bh * HDIM * SEQ;
  const unsigned short* vb = vt + (size_t)bh * HDIM * SEQ;
  const int frow = lane & 15;
  const int fk = (lane >> 4) * 8;

  f32x4 accG[4], accP[4];
#pragma unroll
  for (int j = 0; j < 4; ++j) {
    accG[j] = f32x4{0.f, 0.f, 0.f, 0.f};
    accP[j] = f32x4{0.f, 0.f, 0.f, 0.f};
  }
  for (int nb = 0; nb < SEQ; nb += 32) {
    bf16x8 af = *(const bf16x8*)&kb[(size_t)(wave * 16 + frow) * SEQ + nb + fk];  // i-tile = wave
    bf16x8 kf[4], vf[4];
#pragma unroll
    for (int j = 0; j < 4; ++j)
      kf[j] = *(const bf16x8*)&kb[(size_t)(j * 16 + frow) * SEQ + nb + fk];
#pragma unroll
    for (int j = 0; j < 4; ++j)
      vf[j] = *(const bf16x8*)&vb[(size_t)(j * 16 + frow) * SEQ + nb + fk];
#pragma unroll
    for (int j = 0; j < 4; ++j) {
      accG[j] = __builtin_amdgcn_mfma_f32_16x16x32_bf16(af, kf[j], accG[j], 0, 0, 0);
      accP[j] = __builtin_amdgcn_mfma_f32_16x16x32_bf16(af, vf[j], accP[j], 0, 0, 0);
    }
  }
  const float invN = 1.0f / (float)SEQ;
  const int orow = wave * 16 + (lane >> 4) * 4;
#pragma unroll
  for (int j = 0; j < 4; ++j)
#pragma unroll
    for (int r = 0; r < 4; ++r) {
      Gs[orow + r][j * 16 + frow] = accG[j][r] * invN;
      Ps[orow + r][j * 16 + frow] = accP[j][r] * invN;
    }

  {
    float sk_ = 0.f, sv_ = 0.f;
    const unsigned short* kr = &kb[(size_t)lane * SEQ + wave * 256];
    const unsigned short* vr = &vb[(size_t)lane * SEQ + wave * 256];
    for (int nn = 0; nn < 256; nn += 8) {
      uint4 a = *(const uint4*)&kr[nn];
      uint4 c = *(const uint4*)&vr[nn];
      const unsigned short* pa = (const unsigned short*)&a;
      const unsigned short* pc = (const unsigned short*)&c;
#pragma unroll
      for (int jj = 0; jj < 8; ++jj) { sk_ += b2f(pa[jj]); sv_ += b2f(pc[jj]); }
    }
    mkp[wave][lane] = sk_;
    mvp[wave][lane] = sv_;
  }
  __syncthreads();

  const int r = tid >> 2;
  const int c0 = (tid & 3) * 16;
  if (tid < 64) {
    mks[tid] = (mkp[0][tid] + mkp[1][tid] + mkp[2][tid] + mkp[3][tid]) * invN;
    mvs[tid] = (mvp[0][tid] + mvp[1][tid] + mvp[2][tid] + mvp[3][tid]) * invN;
    bs[tid] = 0.f;
  }
#pragma unroll
  for (int c = 0; c < 16; ++c) Ws[r][c0 + c] = 0.f;
  __syncthreads();

  for (int it = 0; it < 4; ++it) {
    float wn[16];
#pragma unroll
    for (int c = 0; c < 16; ++c)
      wn[c] = Ws[r][c0 + c] + Ps[r][c0 + c] - mks[r] * bs[c0 + c];
    for (int j = 0; j < 64; ++j) {
      float g = Gs[r][j];
#pragma unroll
      for (int c = 0; c < 16; ++c) wn[c] -= g * Ws[j][c0 + c];
    }
    float bn = 0.f;
    if (tid < 64) {
      bn = mvs[tid];
      for (int j = 0; j < 64; ++j) bn -= mks[j] * Ws[j][tid];
    }
    __syncthreads();
#pragma unroll
    for (int c = 0; c < 16; ++c) Ws[r][c0 + c] = wn[c];
    if (tid < 64) bs[tid] = bn;
    __syncthreads();
  }

  unsigned short* wout = Wtb + (size_t)bh * HDIM * HDIM;
#pragma unroll
  for (int c = 0; c < 16; ++c)
    wout[(size_t)(c0 + c) * HDIM + r] = f2b(Ws[r][c0 + c]);
  if (tid < 64) bvec[(size_t)bh * HDIM + tid] = bs[tid];
}

// ------------- attn[m][h*64+dd] = sum_j q[m][j] W[j][dd] + b[dd] (bf16 out) -------------
__global__ __launch_bounds__(256) void attn_qw(const unsigned short* __restrict__ qkvb,
                                               const unsigned short* __restrict__ Wtb,
                                               const float* __restrict__ bvec,
                                               unsigned short* __restrict__ attnb) {
  const int h = blockIdx.y;
  const int m0 = blockIdx.x * 128;
  const int bh = ((m0 >> 10) << 4) + h;
  const int tid = threadIdx.x;
  const int lane = tid & 63, wave = tid >> 6;
  const int frow = lane & 15;
  const int fk = (lane >> 4) * 8;

  f32x4 acc[2][4];
#pragma unroll
  for (int j = 0; j < 4; ++j) {
    float bv = bvec[(size_t)bh * HDIM + j * 16 + frow];
    f32x4 t; t[0] = bv; t[1] = bv; t[2] = bv; t[3] = bv;
    acc[0][j] = t; acc[1][j] = t;
  }

  const unsigned short* qbase = qkvb + (size_t)(m0 + wave * 32) * NQKV + h * HDIM;
  const unsigned short* wbase = Wtb + (size_t)bh * HDIM * HDIM;
#pragma unroll
  for (int s = 0; s < 2; ++s) {
    bf16x8 af[2], wf[4];
#pragma unroll
    for (int i = 0; i < 2; ++i)
      af[i] = *(const bf16x8*)&qbase[(size_t)(i * 16 + frow) * NQKV + s * 32 + fk];
#pragma unroll
    for (int j = 0; j < 4; ++j)
      wf[j] = *(const bf16x8*)&wbase[(size_t)(j * 16 + frow) * HDIM + s * 32 + fk];
#pragma unroll
    for (int i = 0; i < 2; ++i)
#pragma unroll
      for (int j = 0; j < 4; ++j)
        acc[i][j] = __builtin_amdgcn_mfma_f32_16x16x32_bf16(af[i], wf[j], acc[i][j], 0, 0, 0);
  }

  const int orow = m0 + wave * 32 + (lane >> 4) * 4;
#pragma unroll
  for (int i = 0; i < 2; ++i)
#pragma unroll
    for (int j = 0; j < 4; ++j)
#pragma unroll
      for (int rr = 0; rr < 4; ++rr)
        attnb[(size_t)(orow + i * 16 + rr) * DIMC + h * HDIM + j * 16 + frow] = f2b(acc[i][j][rr]);
}

extern "C" void kernel_launch(void* const* d_in, const int* in_sizes, int n_in,
                              void* d_out, int out_size, void* d_ws, size_t ws_size,
                              hipStream_t stream) {
  const float* x      = (const float*)d_in[0];
  const float* w_qkv  = (const float*)d_in[1];
  const float* w_proj = (const float*)d_in[2];
  const float* b_proj = (const float*)d_in[3];

  // workspace layout (bytes)
  char* ws = (char*)d_ws;
  unsigned short* xb    = (unsigned short*)(ws + 0);          //  16,777,216
  unsigned short* wqT   = (unsigned short*)(ws + 16777216);   //   6,291,456
  unsigned short* wpT   = (unsigned short*)(ws + 23068672);   //   2,097,152
  unsigned short* qkvb  = (unsigned short*)(ws + 25165824);   //  50,331,648
  unsigned short* kt    = (unsigned short*)(ws + 75497472);   //  16,777,216
  unsigned short* vt    = (unsigned short*)(ws + 92274688);   //  16,777,216
  unsigned short* attnb = (unsigned short*)(ws + 109051904);  //  16,777,216
  unsigned short* Wtb   = (unsigned short*)(ws + 125829120);  //   1,048,576
  float*          bvec  = (float*)(ws + 126877696);           //      32,768
  if (ws_size < (size_t)126910464) return;  // clean fail if workspace too small

  // allow up to 128 KiB dynamic LDS (idempotent, host-side)
  hipFuncSetAttribute((const void*)g_main256, hipFuncAttributeMaxDynamicSharedMemorySize, 131072);
  hipFuncSetAttribute((const void*)g_main128, hipFuncAttributeMaxDynamicSharedMemorySize, 131072);
  hipFuncSetAttribute((const void*)g_ab1, hipFuncAttributeMaxDynamicSharedMemorySize, 131072);
  hipFuncSetAttribute((const void*)g_ab2, hipFuncAttributeMaxDynamicSharedMemorySize, 131072);
  hipFuncSetAttribute((const void*)g_ab3, hipFuncAttributeMaxDynamicSharedMemorySize, 131072);
  hipFuncSetAttribute((const void*)g_ab4, hipFuncAttributeMaxDynamicSharedMemorySize, 131072);

  cvt_bf16<<<8192, 256, 0, stream>>>(x, xb, MROWS * DIMC / 4);
  transpose_cvt<<<dim3(96, 32), dim3(32, 8), 0, stream>>>(w_qkv, wqT, 1024, 3072);
  transpose_cvt<<<dim3(32, 32), dim3(32, 8), 0, stream>>>(w_proj, wpT, 1024, 1024);

  // ---- ablation dispatches (256 blocks = 1/CU, garbage -> qkvb, overwritten) ----
  g_ab4<<<dim3(256), dim3(512), 131072, stream>>>(xb, wqT, qkvb, nullptr, NQKV, 12);  // MFMA+sync
  g_ab3<<<dim3(256), dim3(512), 131072, stream>>>(xb, wqT, qkvb, nullptr, NQKV, 12);  // mem only
  g_ab2<<<dim3(256), dim3(512), 131072, stream>>>(xb, wqT, qkvb, nullptr, NQKV, 12);  // no ds_read
  g_ab1<<<dim3(256), dim3(512), 131072, stream>>>(xb, wqT, qkvb, nullptr, NQKV, 12);  // no stage

  // ---- real pipeline ----
  g_main256<<<dim3(384), dim3(512), 131072, stream>>>(xb, wqT, qkvb, nullptr, NQKV, 12);
  transpose_kv<<<dim3(16, 128, 2), 256, 0, stream>>>(qkvb, kt, vt);
  stats_gd<<<128, 256, 0, stream>>>(kt, vt, Wtb, bvec);
  attn_qw<<<dim3(64, 16), 256, 0, stream>>>(qkvb, Wtb, bvec, attnb);
  g_main128<<<dim3(256), dim3(512), 98304, stream>>>(attnb, wpT, d_out, b_proj, DIMC, 4);
}

// Round 8
// 198.244 us; speedup vs baseline: 1.6039x; 1.6039x over previous
//
#include <hip/hip_runtime.h>

// MTTT attention, MI355X gfx950.
// B=8, N=1024, C=1024, H=16, d=64, INNER_ITR=4, INNER_LR=1.0
//
// Algebra: the inner GD loop only needs G=k^Tk/N, P=k^Tv/N, mk, mv:
//   W <- W + P - G*W - mk (x) b ;  b <- mv - mk*W   (old W,b on RHS)
// which is an exact rearrangement of the reference iteration.
//
// Round 8: occupancy-first GEMM. Ablation (r7) showed no component alone
// reproduces the 77us; with 1 block/CU the per-iter latency is exposed.
// Fix: small tiles/LDS/VGPR so 2-4 blocks/CU co-reside (m97 mechanism),
// ring-3 LDS with depth-2 prefetch and counted vmcnt.

#define SEQ    1024
#define NBATCH 8
#define DIMC   1024
#define NHEAD  16
#define HDIM   64
#define MROWS  8192      // NBATCH*SEQ
#define NQKV   3072

typedef __attribute__((ext_vector_type(8))) __bf16 bf16x8;
typedef __attribute__((ext_vector_type(4))) float  f32x4;

__device__ __forceinline__ unsigned short f2b(float f) {
  union { float f; unsigned int u; } v; v.f = f;
  unsigned int r = (v.u + 0x7FFFu + ((v.u >> 16) & 1u)) >> 16; // RNE
  return (unsigned short)r;
}
__device__ __forceinline__ float b2f(unsigned short u) {
  union { unsigned int u; float f; } v; v.u = ((unsigned int)u) << 16;
  return v.f;
}

// async global->LDS, 16B per lane; LDS dest = wave-uniform base + lane*16
__device__ __forceinline__ void load_lds16(const void* g, void* l) {
  __builtin_amdgcn_global_load_lds(
      (__attribute__((address_space(1))) void*)(void*)(g),
      (__attribute__((address_space(3))) void*)(l), 16, 0, 0);
}

#define FENCE asm volatile("" ::: "memory")
#define BAR   __builtin_amdgcn_s_barrier()

// ---------------- fp32 -> bf16 convert (vectorized) ----------------
__global__ __launch_bounds__(256) void cvt_bf16(const float* __restrict__ in,
                                                unsigned short* __restrict__ out,
                                                int n4) {
  int i = blockIdx.x * 256 + threadIdx.x;
  if (i >= n4) return;
  float4 v = ((const float4*)in)[i];
  ushort4 o;
  o.x = f2b(v.x); o.y = f2b(v.y); o.z = f2b(v.z); o.w = f2b(v.w);
  ((ushort4*)out)[i] = o;
}

// ------------- fp32 (R x Cc) -> bf16 transposed (Cc x R) -------------
__global__ __launch_bounds__(256) void transpose_cvt(const float* __restrict__ in,
                                                     unsigned short* __restrict__ out,
                                                     int R, int Cc) {
  __shared__ unsigned short tile[32][33];
  int c0 = blockIdx.x * 32, r0 = blockIdx.y * 32;
  int tx = threadIdx.x, ty = threadIdx.y;
  for (int i = ty; i < 32; i += 8)
    tile[i][tx] = f2b(in[(size_t)(r0 + i) * Cc + c0 + tx]);
  __syncthreads();
  for (int i = ty; i < 32; i += 8)
    out[(size_t)(c0 + i) * R + r0 + tx] = tile[tx][i];
}

// =====================================================================
// Occupancy-first NT bf16 GEMM, K fixed at 1024.
//   C[m][n] = sum_k A[m][k] * BT[n][k]  (+bias, fp32 out, if STORE_F32)
// Tile BM x BN, wave tile 64x64 (WM x WN waves), BK=32, 32 K-iters.
// LDS ring of 3 K-tiles, prefetch depth 2, counted vmcnt(CALLS) per iter
// (vmcnt(0) only for the last two iters). One barrier per iter.
//   iter t: stage(t+2) || ds_read buf[t%3] -> (auto lgkm) MFMA x16
//           -> vmcnt(CALLS) -> barrier
// Hazards: RAW: reads of tile t waited at end of t-1 (vmcnt leaves only
// stage(t+1) in flight). WAR: stage(t+2) overwrites buf read at t-1;
// those ds_reads completed (lgkm) before t-1's barrier. Verified incl.
// prologue and tail.
// LDS rows 64B (BK=32), swizzle: 16B chunk c stored at c ^ (row&3);
// source pre-swizzled so global_load_lds' linear dest yields it; read
// XOR is per-lane constant. 64-lane frag read covers each row fully ->
// 8 rows/bank-half -> conflict-free.
// MFMA operands swapped (mfma(B,A)): thread's 4 acc regs = 4 consecutive
// output COLUMNS -> packed ushort4/float4 stores.
// Occupancy: launch_bounds(threads,4) caps VGPR at 128 -> 4 waves/SIMD:
//   qkv (512thr, 72KiB): 2 blocks/CU; proj (256thr, 48KiB): 4 blocks/CU.
// =====================================================================
template <int BM, int BN, int WM, int WN, int STORE_F32>
__global__ __launch_bounds__(WM * WN * 64, 4)
void gemm_r3(const unsigned short* __restrict__ A,
             const unsigned short* __restrict__ BT,
             void* __restrict__ Cout,
             const float* __restrict__ bias,
             int N, int NBN) {
  constexpr int THREADS = WM * WN * 64;
  constexpr int TR      = THREADS / 4;        // 64B rows covered per call
  constexpr int ABYTES  = BM * 64;            // A K-tile bytes
  constexpr int TBYTES  = (BM + BN) * 64;     // A+B K-tile bytes
  constexpr int CALLS   = TBYTES / (THREADS * 16);
  constexpr int NT      = 32;                 // K / 32

  extern __shared__ __align__(16) char ldsb[];

  const int tid  = threadIdx.x;
  const int lane = tid & 63, wave = tid >> 6;
  const int wr = wave / WN, wc = wave % WN;
  const int frow = lane & 15, g4 = lane >> 4;
  const int cz = (g4 ^ (frow & 3)) * 16;      // swizzled chunk byte offset

  // XCD-aware bijective block swizzle (gridDim.x % 8 == 0)
  const int cpx = gridDim.x >> 3;
  const int wg  = (blockIdx.x & 7) * cpx + (blockIdx.x >> 3);
  const int bm = wg / NBN, bn = wg % NBN;
  const size_t m0 = (size_t)bm * BM, n0 = (size_t)bn * BN;

  // staging source: thread t covers LDS row c*TR + (t>>2), chunk t&3,
  // which must hold global chunk (t&3) ^ (row&3)
  const int trow = tid >> 2;
  const int scol = ((tid & 3) ^ (trow & 3)) * 8;  // element offset
  const unsigned short* psrc[CALLS];
#pragma unroll
  for (int c = 0; c < CALLS; ++c) {
    const int rr = c * TR + trow;
    psrc[c] = (rr < BM) ? (A + (m0 + rr) * 1024 + scol)
                        : (BT + (n0 + rr - BM) * 1024 + scol);
  }

  f32x4 acc[4][4];
  if (STORE_F32) {
#pragma unroll
    for (int j = 0; j < 4; ++j) {
      float4 bv = *(const float4*)&bias[n0 + wc * 64 + j * 16 + g4 * 4];
      f32x4 t; t[0] = bv.x; t[1] = bv.y; t[2] = bv.z; t[3] = bv.w;
#pragma unroll
      for (int i = 0; i < 4; ++i) acc[i][j] = t;
    }
  } else {
#pragma unroll
    for (int i = 0; i < 4; ++i)
#pragma unroll
      for (int j = 0; j < 4; ++j) acc[i][j] = f32x4{0.f, 0.f, 0.f, 0.f};
  }

  auto stage = [&](int tk, int buf) {
    char* base = ldsb + buf * TBYTES + wave * 1024;
#pragma unroll
    for (int c = 0; c < CALLS; ++c)
      load_lds16(psrc[c] + tk * 32, base + c * (THREADS * 16));
  };

  const int aoff = (wr * 64 + frow) * 64 + cz;
  const int boff = ABYTES + (wc * 64 + frow) * 64 + cz;

  // prologue: tiles 0,1 -> bufs 0,1; wait tile0 (tile1 stays in flight)
  stage(0, 0); stage(1, 1);
  asm volatile("s_waitcnt vmcnt(%0)" :: "i"(CALLS) : "memory");
  FENCE; BAR;

  int bcur = 0, bpre = 2;
#pragma unroll 1
  for (int t = 0; t < NT; ++t) {
    if (t + 2 < NT) stage(t + 2, bpre);
    const char* rb = ldsb + bcur * TBYTES;
    bf16x8 af[4], bq[4];
#pragma unroll
    for (int i = 0; i < 4; ++i) af[i] = *(const bf16x8*)(rb + aoff + i * 1024);
#pragma unroll
    for (int j = 0; j < 4; ++j) bq[j] = *(const bf16x8*)(rb + boff + j * 1024);
#pragma unroll
    for (int i = 0; i < 4; ++i)
#pragma unroll
      for (int j = 0; j < 4; ++j)
        acc[i][j] = __builtin_amdgcn_mfma_f32_16x16x32_bf16(bq[j], af[i],
                                                            acc[i][j], 0, 0, 0);
    if (t + 2 < NT) asm volatile("s_waitcnt vmcnt(%0)" :: "i"(CALLS) : "memory");
    else            asm volatile("s_waitcnt vmcnt(0)" ::: "memory");
    FENCE; BAR;
    bcur = (bcur == 2) ? 0 : bcur + 1;
    bpre = (bpre == 2) ? 0 : bpre + 1;
  }

  // epilogue: thread holds 4 consecutive output columns per acc frag
  const size_t mbase = m0 + wr * 64 + frow;
  const size_t nbase = n0 + wc * 64 + g4 * 4;
  if (STORE_F32) {
    float* C = (float*)Cout;
#pragma unroll
    for (int i = 0; i < 4; ++i)
#pragma unroll
      for (int j = 0; j < 4; ++j) {
        float4 o; o.x = acc[i][j][0]; o.y = acc[i][j][1];
        o.z = acc[i][j][2]; o.w = acc[i][j][3];
        *(float4*)&C[(mbase + i * 16) * N + nbase + j * 16] = o;
      }
  } else {
    unsigned short* C = (unsigned short*)Cout;
#pragma unroll
    for (int i = 0; i < 4; ++i)
#pragma unroll
      for (int j = 0; j < 4; ++j) {
        ushort4 o; o.x = f2b(acc[i][j][0]); o.y = f2b(acc[i][j][1]);
        o.z = f2b(acc[i][j][2]); o.w = f2b(acc[i][j][3]);
        *(ushort4*)&C[(mbase + i * 16) * N + nbase + j * 16] = o;
      }
  }
}

// ------------- k,v: qkv layout (m, 3C) -> per-head d-major [bh][d][N] -------------
__global__ __launch_bounds__(256) void transpose_kv(const unsigned short* __restrict__ qkvb,
                                                    unsigned short* __restrict__ kt,
                                                    unsigned short* __restrict__ vt) {
  __shared__ unsigned short tile[64][80];  // stride 160B: 16B-aligned rows
  const int nc = blockIdx.x * 64;
  const int bh = blockIdx.y;
  const int which = blockIdx.z;           // 0 -> k (col base C), 1 -> v (col base 2C)
  const int b = bh >> 4, h = bh & 15;
  const int tid = threadIdx.x;
  const unsigned short* src = qkvb + (size_t)(b * SEQ + nc) * NQKV + (which + 1) * DIMC + h * HDIM;
  for (int idx = tid; idx < 512; idx += 256) {
    int rr = idx >> 3, ss = (idx & 7) * 8;
    *(uint4*)&tile[rr][ss] = *(const uint4*)&src[(size_t)rr * NQKV + ss];
  }
  __syncthreads();
  unsigned short* dst = (which ? vt : kt) + (size_t)bh * HDIM * SEQ;
  for (int idx = tid; idx < 512; idx += 256) {
    int dd = idx >> 3, ns = (idx & 7) * 8;
    alignas(16) unsigned short tmp[8];
#pragma unroll
    for (int jj = 0; jj < 8; ++jj) tmp[jj] = tile[ns + jj][dd];
    *(uint4*)&dst[(size_t)dd * SEQ + nc + ns] = *(const uint4*)tmp;
  }
}

// ------------- per-(b,h): G,P via MFMA + mk,mv + 4 GD iters -> W^T (bf16), b -------------
__global__ __launch_bounds__(256) void stats_gd(const unsigned short* __restrict__ kt,
                                                const unsigned short* __restrict__ vt,
                                                unsigned short* __restrict__ Wtb,
                                                float* __restrict__ bvec) {
  __shared__ float Gs[64][68];
  __shared__ float Ps[64][68];
  __shared__ float Ws[64][68];
  __shared__ float mkp[4][64], mvp[4][64];
  __shared__ float mks[64], mvs[64], bs[64];

  const int bh = blockIdx.x;
  const int tid = threadIdx.x;
  const int lane = tid & 63, wave = tid >> 6;
  const unsigned short* kb = kt + (size_t)bh * HDIM * SEQ;
  const unsigned short* vb = vt + (size_t)bh * HDIM * SEQ;
  const int frow = lane & 15;
  const int fk = (lane >> 4) * 8;

  f32x4 accG[4], accP[4];
#pragma unroll
  for (int j = 0; j < 4; ++j) {
    accG[j] = f32x4{0.f, 0.f, 0.f, 0.f};
    accP[j] = f32x4{0.f, 0.f, 0.f, 0.f};
  }
  for (int nb = 0; nb < SEQ; nb += 32) {
    bf16x8 af = *(const bf16x8*)&kb[(size_t)(wave * 16 + frow) * SEQ + nb + fk];  // i-tile = wave
    bf16x8 kf[4], vf[4];
#pragma unroll
    for (int j = 0; j < 4; ++j)
      kf[j] = *(const bf16x8*)&kb[(size_t)(j * 16 + frow) * SEQ + nb + fk];
#pragma unroll
    for (int j = 0; j < 4; ++j)
      vf[j] = *(const bf16x8*)&vb[(size_t)(j * 16 + frow) * SEQ + nb + fk];
#pragma unroll
    for (int j = 0; j < 4; ++j) {
      accG[j] = __builtin_amdgcn_mfma_f32_16x16x32_bf16(af, kf[j], accG[j], 0, 0, 0);
      accP[j] = __builtin_amdgcn_mfma_f32_16x16x32_bf16(af, vf[j], accP[j], 0, 0, 0);
    }
  }
  const float invN = 1.0f / (float)SEQ;
  const int orow = wave * 16 + (lane >> 4) * 4;
#pragma unroll
  for (int j = 0; j < 4; ++j)
#pragma unroll
    for (int r = 0; r < 4; ++r) {
      Gs[orow + r][j * 16 + frow] = accG[j][r] * invN;
      Ps[orow + r][j * 16 + frow] = accP[j][r] * invN;
    }

  {
    float sk_ = 0.f, sv_ = 0.f;
    const unsigned short* kr = &kb[(size_t)lane * SEQ + wave * 256];
    const unsigned short* vr = &vb[(size_t)lane * SEQ + wave * 256];
    for (int nn = 0; nn < 256; nn += 8) {
      uint4 a = *(const uint4*)&kr[nn];
      uint4 c = *(const uint4*)&vr[nn];
      const unsigned short* pa = (const unsigned short*)&a;
      const unsigned short* pc = (const unsigned short*)&c;
#pragma unroll
      for (int jj = 0; jj < 8; ++jj) { sk_ += b2f(pa[jj]); sv_ += b2f(pc[jj]); }
    }
    mkp[wave][lane] = sk_;
    mvp[wave][lane] = sv_;
  }
  __syncthreads();

  const int r = tid >> 2;
  const int c0 = (tid & 3) * 16;
  if (tid < 64) {
    mks[tid] = (mkp[0][tid] + mkp[1][tid] + mkp[2][tid] + mkp[3][tid]) * invN;
    mvs[tid] = (mvp[0][tid] + mvp[1][tid] + mvp[2][tid] + mvp[3][tid]) * invN;
    bs[tid] = 0.f;
  }
#pragma unroll
  for (int c = 0; c < 16; ++c) Ws[r][c0 + c] = 0.f;
  __syncthreads();

  for (int it = 0; it < 4; ++it) {
    float wn[16];
#pragma unroll
    for (int c = 0; c < 16; ++c)
      wn[c] = Ws[r][c0 + c] + Ps[r][c0 + c] - mks[r] * bs[c0 + c];
    for (int j = 0; j < 64; ++j) {
      float g = Gs[r][j];
#pragma unroll
      for (int c = 0; c < 16; ++c) wn[c] -= g * Ws[j][c0 + c];
    }
    float bn = 0.f;
    if (tid < 64) {
      bn = mvs[tid];
      for (int j = 0; j < 64; ++j) bn -= mks[j] * Ws[j][tid];
    }
    __syncthreads();
#pragma unroll
    for (int c = 0; c < 16; ++c) Ws[r][c0 + c] = wn[c];
    if (tid < 64) bs[tid] = bn;
    __syncthreads();
  }

  unsigned short* wout = Wtb + (size_t)bh * HDIM * HDIM;
#pragma unroll
  for (int c = 0; c < 16; ++c)
    wout[(size_t)(c0 + c) * HDIM + r] = f2b(Ws[r][c0 + c]);
  if (tid < 64) bvec[(size_t)bh * HDIM + tid] = bs[tid];
}

// ------------- attn[m][h*64+dd] = sum_j q[m][j] W[j][dd] + b[dd] (bf16 out) -------------
__global__ __launch_bounds__(256) void attn_qw(const unsigned short* __restrict__ qkvb,
                                               const unsigned short* __restrict__ Wtb,
                                               const float* __restrict__ bvec,
                                               unsigned short* __restrict__ attnb) {
  const int h = blockIdx.y;
  const int m0 = blockIdx.x * 128;
  const int bh = ((m0 >> 10) << 4) + h;
  const int tid = threadIdx.x;
  const int lane = tid & 63, wave = tid >> 6;
  const int frow = lane & 15;
  const int fk = (lane >> 4) * 8;

  f32x4 acc[2][4];
#pragma unroll
  for (int j = 0; j < 4; ++j) {
    float bv = bvec[(size_t)bh * HDIM + j * 16 + frow];
    f32x4 t; t[0] = bv; t[1] = bv; t[2] = bv; t[3] = bv;
    acc[0][j] = t; acc[1][j] = t;
  }

  const unsigned short* qbase = qkvb + (size_t)(m0 + wave * 32) * NQKV + h * HDIM;
  const unsigned short* wbase = Wtb + (size_t)bh * HDIM * HDIM;
#pragma unroll
  for (int s = 0; s < 2; ++s) {
    bf16x8 af[2], wf[4];
#pragma unroll
    for (int i = 0; i < 2; ++i)
      af[i] = *(const bf16x8*)&qbase[(size_t)(i * 16 + frow) * NQKV + s * 32 + fk];
#pragma unroll
    for (int j = 0; j < 4; ++j)
      wf[j] = *(const bf16x8*)&wbase[(size_t)(j * 16 + frow) * HDIM + s * 32 + fk];
#pragma unroll
    for (int i = 0; i < 2; ++i)
#pragma unroll
      for (int j = 0; j < 4; ++j)
        acc[i][j] = __builtin_amdgcn_mfma_f32_16x16x32_bf16(af[i], wf[j], acc[i][j], 0, 0, 0);
  }

  const int orow = m0 + wave * 32 + (lane >> 4) * 4;
#pragma unroll
  for (int i = 0; i < 2; ++i)
#pragma unroll
    for (int j = 0; j < 4; ++j)
#pragma unroll
      for (int rr = 0; rr < 4; ++rr)
        attnb[(size_t)(orow + i * 16 + rr) * DIMC + h * HDIM + j * 16 + frow] = f2b(acc[i][j][rr]);
}

extern "C" void kernel_launch(void* const* d_in, const int* in_sizes, int n_in,
                              void* d_out, int out_size, void* d_ws, size_t ws_size,
                              hipStream_t stream) {
  const float* x      = (const float*)d_in[0];
  const float* w_qkv  = (const float*)d_in[1];
  const float* w_proj = (const float*)d_in[2];
  const float* b_proj = (const float*)d_in[3];

  // workspace layout (bytes)
  char* ws = (char*)d_ws;
  unsigned short* xb    = (unsigned short*)(ws + 0);          //  16,777,216
  unsigned short* wqT   = (unsigned short*)(ws + 16777216);   //   6,291,456
  unsigned short* wpT   = (unsigned short*)(ws + 23068672);   //   2,097,152
  unsigned short* qkvb  = (unsigned short*)(ws + 25165824);   //  50,331,648
  unsigned short* kt    = (unsigned short*)(ws + 75497472);   //  16,777,216
  unsigned short* vt    = (unsigned short*)(ws + 92274688);   //  16,777,216
  unsigned short* attnb = (unsigned short*)(ws + 109051904);  //  16,777,216
  unsigned short* Wtb   = (unsigned short*)(ws + 125829120);  //   1,048,576
  float*          bvec  = (float*)(ws + 126877696);           //      32,768
  if (ws_size < (size_t)126910464) return;  // clean fail if workspace too small

  hipFuncSetAttribute((const void*)gemm_r3<128, 256, 2, 4, 0>,
                      hipFuncAttributeMaxDynamicSharedMemorySize, 73728);
  hipFuncSetAttribute((const void*)gemm_r3<128, 128, 2, 2, 1>,
                      hipFuncAttributeMaxDynamicSharedMemorySize, 49152);

  cvt_bf16<<<8192, 256, 0, stream>>>(x, xb, MROWS * DIMC / 4);
  transpose_cvt<<<dim3(96, 32), dim3(32, 8), 0, stream>>>(w_qkv, wqT, 1024, 3072);
  transpose_cvt<<<dim3(32, 32), dim3(32, 8), 0, stream>>>(w_proj, wpT, 1024, 1024);
  // qkv = xb @ wqT^T : M=8192, N=3072 -> 64*12 = 768 blocks (128x256 tiles)
  gemm_r3<128, 256, 2, 4, 0><<<dim3(768), dim3(512), 73728, stream>>>(xb, wqT, qkvb, nullptr, NQKV, 12);
  transpose_kv<<<dim3(16, 128, 2), 256, 0, stream>>>(qkvb, kt, vt);
  stats_gd<<<128, 256, 0, stream>>>(kt, vt, Wtb, bvec);
  attn_qw<<<dim3(64, 16), 256, 0, stream>>>(qkvb, Wtb, bvec, attnb);
  // out = attnb @ wpT^T + b : M=8192, N=1024 -> 64*8 = 512 blocks (128x128 tiles)
  gemm_r3<128, 128, 2, 2, 1><<<dim3(512), dim3(256), 49152, stream>>>(attnb, wpT, d_out, b_proj, DIMC, 8);
}